// Round 2
// baseline (10068.394 us; speedup 1.0000x reference)
//
#include <hip/hip_runtime.h>
#include <math.h>

// Problem sizes (fixed): B=16, M=256, N=256, C=64, OUT=64, modes=32, FF_HID=256
#define TWO_PI_OVER_256 0.024543692606170259f

// ws float offsets
#define WS_CTAB 0        // ctabT[n*32+k] = cos(2pi*k*n/256)
#define WS_STAB 8192     // stabT[n*32+k] = sin(2pi*k*n/256)
#define WS_W1RE 16384    // w1re_t[k*4096 + c*64 + o]
#define WS_W1IM 147456
#define WS_W2RE 278528
#define WS_W2IM 409600
#define WS_FW1T 540672   // ffw1_t[j*64 + c]
// total ws floats = 557056 (~2.2 MB)

__global__ __launch_bounds__(256) void trig_init(float* __restrict__ ws) {
    int id = blockIdx.x * 256 + threadIdx.x;   // 8192 threads
    int k = id >> 8, n = id & 255;
    // exact integer angle reduction: argument stays in [0, 2pi)
    float th = (float)((k * n) & 255) * TWO_PI_OVER_256;
    ws[WS_CTAB + n * 32 + k] = cosf(th);
    ws[WS_STAB + n * 32 + k] = sinf(th);
}

__global__ __launch_bounds__(256) void prep_weights(
        const float* __restrict__ w1re, const float* __restrict__ w1im,
        const float* __restrict__ w2re, const float* __restrict__ w2im,
        const float* __restrict__ ffw1, float* __restrict__ ws) {
    int tid = blockIdx.x * 256 + threadIdx.x;  // 540672 total
    if (tid < 524288) {
        // transpose [c][o][k] -> [k][c][o] for coalesced lane-o reads
        int r = tid & 131071;
        int w = tid >> 17;
        int o = r & 63, cc = (r >> 6) & 63, k = r >> 12;
        const float* src = (w == 0) ? w1re : (w == 1) ? w1im : (w == 2) ? w2re : w2im;
        ws[WS_W1RE + tid] = src[cc * 2048 + o * 32 + k];
    } else {
        // ff_w1 [c][j] -> [j][c] for contiguous per-j float4 reads
        int r = tid - 524288;                   // 16384
        int cc = r & 63, j = r >> 6;
        ws[WS_FW1T + r] = ffw1[cc * 256 + j];
    }
}

// One workgroup per slab (4096 slabs). STRIDE=64: y-branch, slab = x[b,m,:,:]
// (fully contiguous). STRIDE=16384: x-branch, slab = x[b,:,n,:] (64-float rows,
// 64 KB apart). ACC: add into io (io already holds the y-branch output).
// NOTE: default launch bounds. (256,4) was tried in R1: it halved the VGPR
// budget and spilled step1/step3 state — spectral went ~2850 -> ~5400 us.
template<int STRIDE, bool ACC>
__global__ __launch_bounds__(256) void spectral_pass(
        const float* __restrict__ x, float* io,
        const float* __restrict__ ws, int wre_off, int wim_off) {
    __shared__ float Xre[32 * 64], Xim[32 * 64];  // [k*64+c]
    __shared__ float Ar[32 * 64], Ai[32 * 64];    // [k*64+o], pre-scaled
    int t = threadIdx.x;
    size_t off;
    if (STRIDE == 64) {
        off = (size_t)blockIdx.x * 16384;                       // (b*256+m)*N*C
    } else {
        int b = blockIdx.x >> 8, n = blockIdx.x & 255;
        off = (size_t)b * 4194304 + (size_t)n * 64;             // b*M*N*C + n*C
    }
    const float* xb = x + off;
    float* iob = io + off;
    const float* ct = ws + WS_CTAB;
    const float* st = ws + WS_STAB;

    // ---- step 1: forward transform. lane c = t&63, wave handles 8 k's.
    {
        int c = t & 63;
        int kb = (t >> 6) * 8;
        float r0=0,r1=0,r2=0,r3=0,r4=0,r5=0,r6=0,r7=0;
        float i0=0,i1=0,i2=0,i3=0,i4=0,i5=0,i6=0,i7=0;
        for (int p = 0; p < 256; ++p) {
            float v = xb[(size_t)p * STRIDE + c];
            const float4* c4 = (const float4*)(ct + p * 32 + kb);
            const float4* s4 = (const float4*)(st + p * 32 + kb);
            float4 cA = c4[0], cB = c4[1];
            float4 sA = s4[0], sB = s4[1];
            r0 += cA.x * v; r1 += cA.y * v; r2 += cA.z * v; r3 += cA.w * v;
            r4 += cB.x * v; r5 += cB.y * v; r6 += cB.z * v; r7 += cB.w * v;
            i0 += sA.x * v; i1 += sA.y * v; i2 += sA.z * v; i3 += sA.w * v;
            i4 += sB.x * v; i5 += sB.y * v; i6 += sB.z * v; i7 += sB.w * v;
        }
        // rfft ortho: /sqrt(256); e^{-i t}: imag gets minus
        Xre[(kb+0)*64+c] = r0 * 0.0625f;  Xim[(kb+0)*64+c] = i0 * -0.0625f;
        Xre[(kb+1)*64+c] = r1 * 0.0625f;  Xim[(kb+1)*64+c] = i1 * -0.0625f;
        Xre[(kb+2)*64+c] = r2 * 0.0625f;  Xim[(kb+2)*64+c] = i2 * -0.0625f;
        Xre[(kb+3)*64+c] = r3 * 0.0625f;  Xim[(kb+3)*64+c] = i3 * -0.0625f;
        Xre[(kb+4)*64+c] = r4 * 0.0625f;  Xim[(kb+4)*64+c] = i4 * -0.0625f;
        Xre[(kb+5)*64+c] = r5 * 0.0625f;  Xim[(kb+5)*64+c] = i5 * -0.0625f;
        Xre[(kb+6)*64+c] = r6 * 0.0625f;  Xim[(kb+6)*64+c] = i6 * -0.0625f;
        Xre[(kb+7)*64+c] = r7 * 0.0625f;  Xim[(kb+7)*64+c] = i7 * -0.0625f;
    }
    __syncthreads();

    // ---- step 2: per-frequency complex channel mix. lane o = t&63.
    {
        int o = t & 63;
        int kb = (t >> 6) * 8;
        const float* wre = ws + wre_off;
        const float* wim = ws + wim_off;
        for (int kk = 0; kk < 8; ++kk) {
            int k = kb + kk;
            const float* wr = wre + k * 4096 + o;
            const float* wi = wim + k * 4096 + o;
            const float* xr = Xre + k * 64;
            const float* xi = Xim + k * 64;
            float a0=0, a1=0, b0=0, b1=0;
            #pragma unroll 4
            for (int q = 0; q < 16; ++q) {
                float4 xrv = *(const float4*)(xr + q * 4);
                float4 xiv = *(const float4*)(xi + q * 4);
                float w0 = wr[(q*4+0)*64], w1v = wr[(q*4+1)*64];
                float w2v = wr[(q*4+2)*64], w3v = wr[(q*4+3)*64];
                float u0 = wi[(q*4+0)*64], u1 = wi[(q*4+1)*64];
                float u2 = wi[(q*4+2)*64], u3 = wi[(q*4+3)*64];
                a0 += xrv.x*w0 + xrv.y*w1v + xrv.z*w2v + xrv.w*w3v;
                a1 -= xiv.x*u0 + xiv.y*u1 + xiv.z*u2 + xiv.w*u3;
                b0 += xrv.x*u0 + xrv.y*u1 + xrv.z*u2 + xrv.w*u3;
                b1 += xiv.x*w0 + xiv.y*w1v + xiv.z*w2v + xiv.w*w3v;
            }
            // fold irfft ortho 1/16 and the 2x for k>=1 here
            float sc = (k == 0) ? 0.0625f : 0.125f;
            Ar[k*64+o] = (a0 + a1) * sc;
            Ai[k*64+o] = (b0 + b1) * sc;
        }
    }
    __syncthreads();

    // ---- step 3: inverse transform + store. lane o = t&63, wave owns 64 p's.
    {
        int o = t & 63;
        int pb = (t >> 6) * 64;
        float arr[32], aii[32];
        #pragma unroll
        for (int k = 0; k < 32; ++k) {
            arr[k] = Ar[k*64+o];
            aii[k] = Ai[k*64+o];
        }
        for (int p = pb; p < pb + 64; ++p) {
            const float4* c4 = (const float4*)(ct + p * 32);
            const float4* s4 = (const float4*)(st + p * 32);
            float a0=0, a1=0, a2=0, a3=0;
            #pragma unroll
            for (int q = 0; q < 8; ++q) {
                float4 cv = c4[q], sv = s4[q];
                a0 += arr[q*4+0]*cv.x - aii[q*4+0]*sv.x;
                a1 += arr[q*4+1]*cv.y - aii[q*4+1]*sv.y;
                a2 += arr[q*4+2]*cv.z - aii[q*4+2]*sv.z;
                a3 += arr[q*4+3]*cv.w - aii[q*4+3]*sv.w;
            }
            float r = (a0 + a1) + (a2 + a3);
            size_t adr = (size_t)p * STRIDE + o;
            if (ACC) r += iob[adr];   // same thread read+write, no hazard
            iob[adr] = r;
        }
    }
}

// FF (64 -> 256 relu -> 64) + LayerNorm, in-place on io.
// 4 lanes per token: lane q = t&3 owns channels 16q..16q+15. Per-thread state
// is 8 float4 scalars (16 x + 16 y) — no arrays, so nothing can go to scratch.
// (The thread-per-token version kept xv[64]+y[64] allocas: SROA failed on the
// runtime-indexed arrays, VGPR=76 + 673 MB of scratch spill traffic.)
__global__ __launch_bounds__(256) void ff_ln4(
        const float* __restrict__ ws, float* io,
        const float* __restrict__ ffw2, const float* __restrict__ ffb1,
        const float* __restrict__ ffb2, const float* __restrict__ lng,
        const float* __restrict__ lnb) {
    int t = threadIdx.x;
    int q = t & 3;                                     // quarter of the channel dim
    size_t tok = (size_t)blockIdx.x * 64 + (t >> 2);   // 64 tokens per block
    float* xp = io + tok * 64 + q * 16;

    // load this lane's 16 input channels
    float4 xa = ((const float4*)xp)[0];
    float4 xb = ((const float4*)xp)[1];
    float4 xc = ((const float4*)xp)[2];
    float4 xd = ((const float4*)xp)[3];

    // y accumulators init with this lane's slice of ffb2
    const float4* b2 = (const float4*)(ffb2 + q * 16);
    float4 y0 = b2[0], y1 = b2[1], y2 = b2[2], y3 = b2[3];

    const float* w1t = ws + WS_FW1T;                   // [j][c], 256x64
    for (int j = 0; j < 256; ++j) {
        const float4* w1 = (const float4*)(w1t + j * 64 + q * 16);
        float4 a = w1[0], b = w1[1], c = w1[2], d = w1[3];
        float ha = xa.x*a.x + xa.y*a.y + xa.z*a.z + xa.w*a.w;
        float hb = xb.x*b.x + xb.y*b.y + xb.z*b.z + xb.w*b.w;
        float hc = xc.x*c.x + xc.y*c.y + xc.z*c.z + xc.w*c.w;
        float hd = xd.x*d.x + xd.y*d.y + xd.z*d.z + xd.w*d.w;
        float h = (ha + hb) + (hc + hd);
        // reduce the partial dot over the 4-lane group
        h += __shfl_xor(h, 1);
        h += __shfl_xor(h, 2);
        h = fmaxf(h + ffb1[j], 0.f);
        const float4* w2 = (const float4*)(ffw2 + j * 64 + q * 16);
        float4 wa = w2[0], wb = w2[1], wc = w2[2], wd = w2[3];
        y0.x += h*wa.x; y0.y += h*wa.y; y0.z += h*wa.z; y0.w += h*wa.w;
        y1.x += h*wb.x; y1.y += h*wb.y; y1.z += h*wb.z; y1.w += h*wb.w;
        y2.x += h*wc.x; y2.y += h*wc.y; y2.z += h*wc.z; y2.w += h*wc.w;
        y3.x += h*wd.x; y3.y += h*wd.y; y3.z += h*wd.z; y3.w += h*wd.w;
    }

    // LayerNorm over 64 channels = this lane's 16 + reduce over the 4-lane group
    float s = ((y0.x+y0.y)+(y0.z+y0.w)) + ((y1.x+y1.y)+(y1.z+y1.w))
            + ((y2.x+y2.y)+(y2.z+y2.w)) + ((y3.x+y3.y)+(y3.z+y3.w));
    s += __shfl_xor(s, 1);
    s += __shfl_xor(s, 2);
    float mu = s * 0.015625f;
    float d0, d1, d2, d3, v = 0.f;
    d0=y0.x-mu; d1=y0.y-mu; d2=y0.z-mu; d3=y0.w-mu; v += (d0*d0+d1*d1)+(d2*d2+d3*d3);
    d0=y1.x-mu; d1=y1.y-mu; d2=y1.z-mu; d3=y1.w-mu; v += (d0*d0+d1*d1)+(d2*d2+d3*d3);
    d0=y2.x-mu; d1=y2.y-mu; d2=y2.z-mu; d3=y2.w-mu; v += (d0*d0+d1*d1)+(d2*d2+d3*d3);
    d0=y3.x-mu; d1=y3.y-mu; d2=y3.z-mu; d3=y3.w-mu; v += (d0*d0+d1*d1)+(d2*d2+d3*d3);
    v += __shfl_xor(v, 1);
    v += __shfl_xor(v, 2);
    float rs = rsqrtf(v * 0.015625f + 1e-5f);

    const float4* g4 = (const float4*)(lng + q * 16);
    const float4* n4 = (const float4*)(lnb + q * 16);
    float4 g, n, r;
    g = g4[0]; n = n4[0];
    r.x=(y0.x-mu)*rs*g.x+n.x; r.y=(y0.y-mu)*rs*g.y+n.y; r.z=(y0.z-mu)*rs*g.z+n.z; r.w=(y0.w-mu)*rs*g.w+n.w;
    ((float4*)xp)[0] = r;
    g = g4[1]; n = n4[1];
    r.x=(y1.x-mu)*rs*g.x+n.x; r.y=(y1.y-mu)*rs*g.y+n.y; r.z=(y1.z-mu)*rs*g.z+n.z; r.w=(y1.w-mu)*rs*g.w+n.w;
    ((float4*)xp)[1] = r;
    g = g4[2]; n = n4[2];
    r.x=(y2.x-mu)*rs*g.x+n.x; r.y=(y2.y-mu)*rs*g.y+n.y; r.z=(y2.z-mu)*rs*g.z+n.z; r.w=(y2.w-mu)*rs*g.w+n.w;
    ((float4*)xp)[2] = r;
    g = g4[3]; n = n4[3];
    r.x=(y3.x-mu)*rs*g.x+n.x; r.y=(y3.y-mu)*rs*g.y+n.y; r.z=(y3.z-mu)*rs*g.z+n.z; r.w=(y3.w-mu)*rs*g.w+n.w;
    ((float4*)xp)[3] = r;
}

extern "C" void kernel_launch(void* const* d_in, const int* in_sizes, int n_in,
                              void* d_out, int out_size, void* d_ws, size_t ws_size,
                              hipStream_t stream) {
    (void)in_sizes; (void)n_in; (void)out_size; (void)ws_size;
    const float* x    = (const float*)d_in[0];
    const float* w1re = (const float*)d_in[1];
    const float* w1im = (const float*)d_in[2];
    const float* w2re = (const float*)d_in[3];
    const float* w2im = (const float*)d_in[4];
    const float* ffw1 = (const float*)d_in[5];
    const float* ffb1 = (const float*)d_in[6];
    const float* ffw2 = (const float*)d_in[7];
    const float* ffb2 = (const float*)d_in[8];
    const float* lng  = (const float*)d_in[9];
    const float* lnb  = (const float*)d_in[10];
    float* out = (float*)d_out;
    float* ws  = (float*)d_ws;

    trig_init<<<32, 256, 0, stream>>>(ws);
    prep_weights<<<2112, 256, 0, stream>>>(w1re, w1im, w2re, w2im, ffw1, ws);
    // y-branch: writes xy into d_out (scratch)
    spectral_pass<64, false><<<4096, 256, 0, stream>>>(x, out, ws, WS_W1RE, WS_W1IM);
    // x-branch: accumulates xx into d_out
    spectral_pass<16384, true><<<4096, 256, 0, stream>>>(x, out, ws, WS_W2RE, WS_W2IM);
    // FF + LayerNorm in place: 4 lanes per token, 64 tokens per 256-thread block
    ff_ln4<<<16384, 256, 0, stream>>>(ws, out, ffw2, ffb1, ffb2, lng, lnb);
}

// Round 3
// 4843.333 us; speedup vs baseline: 2.0788x; 2.0788x over previous
//
#include <hip/hip_runtime.h>
#include <math.h>

// Problem sizes (fixed): B=16, M=256, N=256, C=64, OUT=64, modes=32, FF_HID=256
#define TWO_PI_OVER_256 0.024543692606170259f

// ws float offsets
#define WS_CTAB 0        // ctabT[n*32+k] = cos(2pi*k*n/256)
#define WS_STAB 8192     // stabT[n*32+k] = sin(2pi*k*n/256)
#define WS_W1RE 16384    // w1re_t[k*4096 + c*64 + o]
#define WS_W1IM 147456
#define WS_W2RE 278528
#define WS_W2IM 409600
#define WS_FW1T 540672   // ffw1_t[j*64 + c]
// total ws floats = 557056 (~2.2 MB)

__global__ __launch_bounds__(256) void trig_init(float* __restrict__ ws) {
    int id = blockIdx.x * 256 + threadIdx.x;   // 8192 threads
    int k = id >> 8, n = id & 255;
    float th = (float)((k * n) & 255) * TWO_PI_OVER_256;
    ws[WS_CTAB + n * 32 + k] = cosf(th);
    ws[WS_STAB + n * 32 + k] = sinf(th);
}

__global__ __launch_bounds__(256) void prep_weights(
        const float* __restrict__ w1re, const float* __restrict__ w1im,
        const float* __restrict__ w2re, const float* __restrict__ w2im,
        const float* __restrict__ ffw1, float* __restrict__ ws) {
    int tid = blockIdx.x * 256 + threadIdx.x;  // 540672 total
    if (tid < 524288) {
        int r = tid & 131071;
        int w = tid >> 17;
        int o = r & 63, cc = (r >> 6) & 63, k = r >> 12;
        const float* src = (w == 0) ? w1re : (w == 1) ? w1im : (w == 2) ? w2re : w2im;
        ws[WS_W1RE + tid] = src[cc * 2048 + o * 32 + k];
    } else {
        int r = tid - 524288;                   // 16384
        int cc = r & 63, j = r >> 6;
        ws[WS_FW1T + r] = ffw1[cc * 256 + j];
    }
}

// One workgroup per slab (4096 slabs). STRIDE=64: y-branch (contiguous slab).
// STRIDE=16384: x-branch. ACC: accumulate into io.
// NO private arrays anywhere: loop-indexed allocas fail SROA and land in
// scratch (rule #20) — step3's arr[32]/aii[32] did exactly that.
template<int STRIDE, bool ACC>
__global__ __launch_bounds__(256) void spectral_pass(
        const float* __restrict__ x, float* io,
        const float* __restrict__ ws, int wre_off, int wim_off) {
    __shared__ float Xre[32 * 64], Xim[32 * 64];  // [k*64+c]
    __shared__ float Ar[32 * 64], Ai[32 * 64];    // [k*64+o], pre-scaled
    int t = threadIdx.x;
    size_t off;
    if (STRIDE == 64) {
        off = (size_t)blockIdx.x * 16384;                       // (b*256+m)*N*C
    } else {
        int b = blockIdx.x >> 8, n = blockIdx.x & 255;
        off = (size_t)b * 4194304 + (size_t)n * 64;             // b*M*N*C + n*C
    }
    const float* xb = x + off;
    float* iob = io + off;
    const float* ct = ws + WS_CTAB;
    const float* st = ws + WS_STAB;

    // ---- step 1: forward transform. lane c = t&63, wave handles 8 k's.
    {
        int c = t & 63;
        int kb = (t >> 6) * 8;
        float r0=0,r1=0,r2=0,r3=0,r4=0,r5=0,r6=0,r7=0;
        float i0=0,i1=0,i2=0,i3=0,i4=0,i5=0,i6=0,i7=0;
        for (int p = 0; p < 256; ++p) {
            float v = xb[(size_t)p * STRIDE + c];
            const float4* c4 = (const float4*)(ct + p * 32 + kb);
            const float4* s4 = (const float4*)(st + p * 32 + kb);
            float4 cA = c4[0], cB = c4[1];
            float4 sA = s4[0], sB = s4[1];
            r0 += cA.x * v; r1 += cA.y * v; r2 += cA.z * v; r3 += cA.w * v;
            r4 += cB.x * v; r5 += cB.y * v; r6 += cB.z * v; r7 += cB.w * v;
            i0 += sA.x * v; i1 += sA.y * v; i2 += sA.z * v; i3 += sA.w * v;
            i4 += sB.x * v; i5 += sB.y * v; i6 += sB.z * v; i7 += sB.w * v;
        }
        Xre[(kb+0)*64+c] = r0 * 0.0625f;  Xim[(kb+0)*64+c] = i0 * -0.0625f;
        Xre[(kb+1)*64+c] = r1 * 0.0625f;  Xim[(kb+1)*64+c] = i1 * -0.0625f;
        Xre[(kb+2)*64+c] = r2 * 0.0625f;  Xim[(kb+2)*64+c] = i2 * -0.0625f;
        Xre[(kb+3)*64+c] = r3 * 0.0625f;  Xim[(kb+3)*64+c] = i3 * -0.0625f;
        Xre[(kb+4)*64+c] = r4 * 0.0625f;  Xim[(kb+4)*64+c] = i4 * -0.0625f;
        Xre[(kb+5)*64+c] = r5 * 0.0625f;  Xim[(kb+5)*64+c] = i5 * -0.0625f;
        Xre[(kb+6)*64+c] = r6 * 0.0625f;  Xim[(kb+6)*64+c] = i6 * -0.0625f;
        Xre[(kb+7)*64+c] = r7 * 0.0625f;  Xim[(kb+7)*64+c] = i7 * -0.0625f;
    }
    __syncthreads();

    // ---- step 2: per-frequency complex channel mix. lane o = t&63.
    {
        int o = t & 63;
        int kb = (t >> 6) * 8;
        const float* wre = ws + wre_off;
        const float* wim = ws + wim_off;
        for (int kk = 0; kk < 8; ++kk) {
            int k = kb + kk;
            const float* wr = wre + k * 4096 + o;
            const float* wi = wim + k * 4096 + o;
            const float* xr = Xre + k * 64;
            const float* xi = Xim + k * 64;
            float a0=0, a1=0, b0=0, b1=0;
            #pragma unroll 4
            for (int q = 0; q < 16; ++q) {
                float4 xrv = *(const float4*)(xr + q * 4);
                float4 xiv = *(const float4*)(xi + q * 4);
                float w0 = wr[(q*4+0)*64], w1v = wr[(q*4+1)*64];
                float w2v = wr[(q*4+2)*64], w3v = wr[(q*4+3)*64];
                float u0 = wi[(q*4+0)*64], u1 = wi[(q*4+1)*64];
                float u2 = wi[(q*4+2)*64], u3 = wi[(q*4+3)*64];
                a0 += xrv.x*w0 + xrv.y*w1v + xrv.z*w2v + xrv.w*w3v;
                a1 -= xiv.x*u0 + xiv.y*u1 + xiv.z*u2 + xiv.w*u3;
                b0 += xrv.x*u0 + xrv.y*u1 + xrv.z*u2 + xrv.w*u3;
                b1 += xiv.x*w0 + xiv.y*w1v + xiv.z*w2v + xiv.w*w3v;
            }
            float sc = (k == 0) ? 0.0625f : 0.125f;
            Ar[k*64+o] = (a0 + a1) * sc;
            Ai[k*64+o] = (b0 + b1) * sc;
        }
    }
    __syncthreads();

    // ---- step 3: inverse transform + store. lane o = t&63, wave owns 64 p's.
    // 32 (re,im) coefficients held in 16 NAMED float4s — nothing in scratch.
    {
        int o = t & 63;
        int pb = (t >> 6) * 64;
        float4 rA, rB, rC, rD, rE, rF, rG, rH;
        float4 iA, iB, iC, iD, iE, iF, iG, iH;
#define LD4(V, ARR, K) V.x = ARR[(K+0)*64+o]; V.y = ARR[(K+1)*64+o]; \
                       V.z = ARR[(K+2)*64+o]; V.w = ARR[(K+3)*64+o];
        LD4(rA, Ar, 0)  LD4(rB, Ar, 4)  LD4(rC, Ar, 8)  LD4(rD, Ar, 12)
        LD4(rE, Ar, 16) LD4(rF, Ar, 20) LD4(rG, Ar, 24) LD4(rH, Ar, 28)
        LD4(iA, Ai, 0)  LD4(iB, Ai, 4)  LD4(iC, Ai, 8)  LD4(iD, Ai, 12)
        LD4(iE, Ai, 16) LD4(iF, Ai, 20) LD4(iG, Ai, 24) LD4(iH, Ai, 28)
#undef LD4
        for (int p = pb; p < pb + 64; ++p) {
            const float4* c4 = (const float4*)(ct + p * 32);
            const float4* s4 = (const float4*)(st + p * 32);
            float a0=0, a1=0, a2=0, a3=0;
            float4 cv, sv;
#define IRT(AR, AI, Q) cv = c4[Q]; sv = s4[Q]; \
            a0 += AR.x*cv.x - AI.x*sv.x; \
            a1 += AR.y*cv.y - AI.y*sv.y; \
            a2 += AR.z*cv.z - AI.z*sv.z; \
            a3 += AR.w*cv.w - AI.w*sv.w;
            IRT(rA, iA, 0) IRT(rB, iB, 1) IRT(rC, iC, 2) IRT(rD, iD, 3)
            IRT(rE, iE, 4) IRT(rF, iF, 5) IRT(rG, iG, 6) IRT(rH, iH, 7)
#undef IRT
            float r = (a0 + a1) + (a2 + a3);
            size_t adr = (size_t)p * STRIDE + o;
            if (ACC) r += iob[adr];   // same thread read+write, no hazard
            iob[adr] = r;
        }
    }
}

// Thread-per-token FF (64 -> 256 relu -> 64) + LayerNorm, in-place on io.
// All state in NAMED float4s (16 x + 16 y): guaranteed registers. The round-0
// version used float[64] allocas -> SROA failed -> 673 MB scratch traffic;
// the round-2 4-lane split had 2 shuffles in every j-chain -> latency-bound.
#define DOT4(V, W) (V.x*W.x + V.y*W.y + V.z*W.z + V.w*W.w)
#define YUP(Y, W)  Y.x += h*W.x; Y.y += h*W.y; Y.z += h*W.z; Y.w += h*W.w;
#define SUM4(Y)    ((Y.x + Y.y) + (Y.z + Y.w))
#define VAR4(Y)    { float dx=Y.x-mu, dy=Y.y-mu, dz=Y.z-mu, dw=Y.w-mu; \
                     v0 += dx*dx; v1 += dy*dy; v2 += dz*dz; v3 += dw*dw; }
#define STO(Y, Q)  { float4 g = g4[Q], bb = n4[Q], r; \
                     r.x = (Y.x-mu)*rs*g.x + bb.x; \
                     r.y = (Y.y-mu)*rs*g.y + bb.y; \
                     r.z = (Y.z-mu)*rs*g.z + bb.z; \
                     r.w = (Y.w-mu)*rs*g.w + bb.w; \
                     xp4[Q] = r; }

__global__ __launch_bounds__(256) void ff_ln(
        const float* __restrict__ ws, float* io,
        const float* __restrict__ ffw2, const float* __restrict__ ffb1,
        const float* __restrict__ ffb2, const float* __restrict__ lng,
        const float* __restrict__ lnb) {
    size_t tok = (size_t)blockIdx.x * 256 + threadIdx.x;   // 1048576 tokens
    float4* xp4 = (float4*)(io + tok * 64);

    float4 x0=xp4[0],  x1=xp4[1],  x2=xp4[2],  x3=xp4[3];
    float4 x4=xp4[4],  x5=xp4[5],  x6=xp4[6],  x7=xp4[7];
    float4 x8=xp4[8],  x9=xp4[9],  xA=xp4[10], xB=xp4[11];
    float4 xC=xp4[12], xD=xp4[13], xE=xp4[14], xF=xp4[15];

    const float4* b2 = (const float4*)ffb2;
    float4 y0=b2[0],  y1=b2[1],  y2=b2[2],  y3=b2[3];
    float4 y4=b2[4],  y5=b2[5],  y6=b2[6],  y7=b2[7];
    float4 y8=b2[8],  y9=b2[9],  yA=b2[10], yB=b2[11];
    float4 yC=b2[12], yD=b2[13], yE=b2[14], yF=b2[15];

    const float* w1t = ws + WS_FW1T;                   // [j][c], 256x64
    for (int j = 0; j < 256; ++j) {
        const float4* w1 = (const float4*)(w1t + j * 64);  // wave-uniform row
        float4 w;
        w = w1[0];  float ha = DOT4(x0, w);
        w = w1[1];  ha += DOT4(x1, w);
        w = w1[2];  ha += DOT4(x2, w);
        w = w1[3];  ha += DOT4(x3, w);
        w = w1[4];  float hb = DOT4(x4, w);
        w = w1[5];  hb += DOT4(x5, w);
        w = w1[6];  hb += DOT4(x6, w);
        w = w1[7];  hb += DOT4(x7, w);
        w = w1[8];  float hc = DOT4(x8, w);
        w = w1[9];  hc += DOT4(x9, w);
        w = w1[10]; hc += DOT4(xA, w);
        w = w1[11]; hc += DOT4(xB, w);
        w = w1[12]; float hd = DOT4(xC, w);
        w = w1[13]; hd += DOT4(xD, w);
        w = w1[14]; hd += DOT4(xE, w);
        w = w1[15]; hd += DOT4(xF, w);
        float h = fmaxf(((ha + hb) + (hc + hd)) + ffb1[j], 0.f);

        const float4* w2 = (const float4*)(ffw2 + j * 64);  // wave-uniform row
        w = w2[0];  YUP(y0, w)
        w = w2[1];  YUP(y1, w)
        w = w2[2];  YUP(y2, w)
        w = w2[3];  YUP(y3, w)
        w = w2[4];  YUP(y4, w)
        w = w2[5];  YUP(y5, w)
        w = w2[6];  YUP(y6, w)
        w = w2[7];  YUP(y7, w)
        w = w2[8];  YUP(y8, w)
        w = w2[9];  YUP(y9, w)
        w = w2[10]; YUP(yA, w)
        w = w2[11]; YUP(yB, w)
        w = w2[12]; YUP(yC, w)
        w = w2[13]; YUP(yD, w)
        w = w2[14]; YUP(yE, w)
        w = w2[15]; YUP(yF, w)
    }

    // LayerNorm over 64
    float s = ((SUM4(y0)+SUM4(y1)) + (SUM4(y2)+SUM4(y3)))
            + ((SUM4(y4)+SUM4(y5)) + (SUM4(y6)+SUM4(y7)))
            + ((SUM4(y8)+SUM4(y9)) + (SUM4(yA)+SUM4(yB)))
            + ((SUM4(yC)+SUM4(yD)) + (SUM4(yE)+SUM4(yF)));
    float mu = s * 0.015625f;
    float v0=0, v1=0, v2=0, v3=0;
    VAR4(y0) VAR4(y1) VAR4(y2) VAR4(y3)
    VAR4(y4) VAR4(y5) VAR4(y6) VAR4(y7)
    VAR4(y8) VAR4(y9) VAR4(yA) VAR4(yB)
    VAR4(yC) VAR4(yD) VAR4(yE) VAR4(yF)
    float rs = rsqrtf(((v0+v1)+(v2+v3)) * 0.015625f + 1e-5f);

    const float4* g4 = (const float4*)lng;
    const float4* n4 = (const float4*)lnb;
    STO(y0, 0)  STO(y1, 1)  STO(y2, 2)  STO(y3, 3)
    STO(y4, 4)  STO(y5, 5)  STO(y6, 6)  STO(y7, 7)
    STO(y8, 8)  STO(y9, 9)  STO(yA, 10) STO(yB, 11)
    STO(yC, 12) STO(yD, 13) STO(yE, 14) STO(yF, 15)
}

extern "C" void kernel_launch(void* const* d_in, const int* in_sizes, int n_in,
                              void* d_out, int out_size, void* d_ws, size_t ws_size,
                              hipStream_t stream) {
    (void)in_sizes; (void)n_in; (void)out_size; (void)ws_size;
    const float* x    = (const float*)d_in[0];
    const float* w1re = (const float*)d_in[1];
    const float* w1im = (const float*)d_in[2];
    const float* w2re = (const float*)d_in[3];
    const float* w2im = (const float*)d_in[4];
    const float* ffw1 = (const float*)d_in[5];
    const float* ffb1 = (const float*)d_in[6];
    const float* ffw2 = (const float*)d_in[7];
    const float* ffb2 = (const float*)d_in[8];
    const float* lng  = (const float*)d_in[9];
    const float* lnb  = (const float*)d_in[10];
    float* out = (float*)d_out;
    float* ws  = (float*)d_ws;

    trig_init<<<32, 256, 0, stream>>>(ws);
    prep_weights<<<2112, 256, 0, stream>>>(w1re, w1im, w2re, w2im, ffw1, ws);
    // y-branch: writes xy into d_out (scratch)
    spectral_pass<64, false><<<4096, 256, 0, stream>>>(x, out, ws, WS_W1RE, WS_W1IM);
    // x-branch: accumulates xx into d_out
    spectral_pass<16384, true><<<4096, 256, 0, stream>>>(x, out, ws, WS_W2RE, WS_W2IM);
    // FF + LayerNorm in place, thread-per-token
    ff_ln<<<4096, 256, 0, stream>>>(ws, out, ffw2, ffb1, ffb2, lng, lnb);
}